// Round 1
// baseline (1076.707 us; speedup 1.0000x reference)
//
#include <hip/hip_runtime.h>
#include <hip/hip_bf16.h>
#include <math.h>

// Problem constants (match reference)
#define NN 100000
#define EE 1600000
#define HH 128
#define GG 2000
#define SS 200
#define CC 10
#define NPG 50   // nodes per graph
#define PGS 10   // graphs per set

// ---------------- CSR build ----------------

__global__ void zero_int_kernel(int* p, int n) {
    int i = blockIdx.x * 256 + threadIdx.x;
    if (i < n) p[i] = 0;
}

__global__ void count_edges_kernel(const int* __restrict__ dst, int* __restrict__ degi, int e) {
    int i = blockIdx.x * 256 + threadIdx.x;
    if (i < e) atomicAdd(&degi[dst[i]], 1);
}

// per-chunk inclusive scan: row_ptr[i+1] = scan(degi)[i] within chunk; bsum[b] = chunk total
__global__ void scan_chunk_kernel(const int* __restrict__ v, int* __restrict__ row_ptr,
                                  int* __restrict__ bsum, int n) {
    __shared__ int s[256];
    int tid = threadIdx.x;
    int i = blockIdx.x * 256 + tid;
    int x = (i < n) ? v[i] : 0;
    s[tid] = x;
    __syncthreads();
    for (int off = 1; off < 256; off <<= 1) {
        int y = (tid >= off) ? s[tid - off] : 0;
        __syncthreads();
        s[tid] += y;
        __syncthreads();
    }
    if (i < n) row_ptr[i + 1] = s[tid];
    if (tid == 255) bsum[blockIdx.x] = s[255];
}

__global__ void scan_bsums_kernel(int* bsum, int nb) {
    __shared__ int s[512];
    int tid = threadIdx.x;
    int x = (tid < nb) ? bsum[tid] : 0;
    s[tid] = x;
    __syncthreads();
    for (int off = 1; off < 512; off <<= 1) {
        int y = (tid >= off) ? s[tid - off] : 0;
        __syncthreads();
        s[tid] += y;
        __syncthreads();
    }
    if (tid < nb) bsum[tid] = s[tid];
}

__global__ void scan_finish_kernel(int* __restrict__ row_ptr, const int* __restrict__ bsum,
                                   int* __restrict__ fill, int n) {
    int i = blockIdx.x * 256 + threadIdx.x;
    if (i < n) {
        if (blockIdx.x > 0) row_ptr[i + 1] += bsum[blockIdx.x - 1];
        fill[i] = 0;
    }
    if (i == 0) row_ptr[0] = 0;
}

__global__ void dinv_kernel(const int* __restrict__ degi, float* __restrict__ dinv, int n) {
    int i = blockIdx.x * 256 + threadIdx.x;
    if (i < n) dinv[i] = 1.0f / sqrtf((float)(degi[i] + 1));  // +1 self loop
}

__global__ void fill_csr_kernel(const int* __restrict__ ei, const int* __restrict__ rp,
                                int* __restrict__ fill, const float* __restrict__ dinv,
                                int* __restrict__ col, float* __restrict__ enorm, int e) {
    int idx = blockIdx.x * 256 + threadIdx.x;
    if (idx >= e) return;
    int s = ei[idx];
    int d = ei[e + idx];
    int pos = atomicAdd(&fill[d], 1);
    int o = rp[d] + pos;
    col[o] = s;
    enorm[o] = dinv[s] * dinv[d];
}

// ---------------- GEMM: Y[n][128] = X[n][128] @ W[128][128] ----------------

__global__ __launch_bounds__(256) void gemm128_kernel(const float* __restrict__ X,
                                                      const float* __restrict__ W,
                                                      float* __restrict__ Y, int nrows) {
    __shared__ float Ws[128 * 128];   // 64 KB
    __shared__ float Xs[64 * 128];    // 32 KB
    int tid = threadIdx.x;
    int row0 = blockIdx.x * 64;
    int nrow = min(64, nrows - row0);

    const float4* W4 = (const float4*)W;
    float4* Ws4 = (float4*)Ws;
#pragma unroll
    for (int i = 0; i < 16; ++i) Ws4[tid + i * 256] = W4[tid + i * 256];

    const float4* X4 = (const float4*)(X + (size_t)row0 * 128);
    float4* Xs4 = (float4*)Xs;
    for (int i = tid; i < nrow * 32; i += 256) Xs4[i] = X4[i];
    __syncthreads();

    int c4 = tid & 31;   // 32 col groups * 4 cols
    int rg = tid >> 5;   // 8 row groups
    for (int r = rg; r < nrow; r += 8) {
        float4 acc = {0.f, 0.f, 0.f, 0.f};
        const float* xr = &Xs[r * 128];
#pragma unroll 8
        for (int k = 0; k < 128; ++k) {
            float xv = xr[k];
            float4 w = Ws4[k * 32 + c4];
            acc.x += xv * w.x;
            acc.y += xv * w.y;
            acc.z += xv * w.z;
            acc.w += xv * w.w;
        }
        ((float4*)(Y + (size_t)(row0 + r) * 128))[c4] = acc;
    }
}

// ---------------- GCN aggregation (gather CSR), + bias + relu ----------------

__global__ __launch_bounds__(256) void aggregate_kernel(const float* __restrict__ hw,
                                                        const int* __restrict__ rp,
                                                        const int* __restrict__ col,
                                                        const float* __restrict__ enorm,
                                                        const float* __restrict__ dinv,
                                                        const float* __restrict__ bias,
                                                        float* __restrict__ outp, int n) {
    int wid = threadIdx.x >> 6;
    int lane = threadIdx.x & 63;
    int i = blockIdx.x * 4 + wid;
    if (i >= n) return;
    const float2* hw2 = (const float2*)hw;
    float di = dinv[i];
    float2 acc;
    {
        float2 v = hw2[(size_t)i * 64 + lane];
        float w = di * di;  // self-loop norm
        acc.x = v.x * w;
        acc.y = v.y * w;
    }
    int j0 = rp[i], j1 = rp[i + 1];
    for (int j = j0; j < j1; ++j) {
        int s = col[j];
        float w = enorm[j];
        float2 v = hw2[(size_t)s * 64 + lane];
        acc.x += w * v.x;
        acc.y += w * v.y;
    }
    float2 bv = ((const float2*)bias)[lane];
    float2 r;
    r.x = fmaxf(acc.x + bv.x, 0.f);
    r.y = fmaxf(acc.y + bv.y, 0.f);
    ((float2*)outp)[(size_t)i * 64 + lane] = r;
}

// ---------------- mean pool (50 consecutive rows per graph) ----------------

__global__ __launch_bounds__(256) void pool_kernel(const float* __restrict__ h,
                                                   float* __restrict__ gemb) {
    int wid = threadIdx.x >> 6;
    int lane = threadIdx.x & 63;
    int g = blockIdx.x * 4 + wid;
    if (g >= GG) return;
    const float2* h2 = (const float2*)h;
    float2 acc = {0.f, 0.f};
    size_t base = (size_t)g * NPG * 64;
    for (int r = 0; r < NPG; ++r) {
        float2 v = h2[base + (size_t)r * 64 + lane];
        acc.x += v.x;
        acc.y += v.y;
    }
    float2 o;
    o.x = acc.x / (float)NPG;
    o.y = acc.y / (float)NPG;
    ((float2*)gemb)[(size_t)g * 64 + lane] = o;
}

// ---------------- DeepSets psi: p_g = tanh(relu(emb W1 + b1) W2 + b2) ----------------

__global__ __launch_bounds__(128) void psi_kernel(const float* __restrict__ gemb,
                                                  const float* __restrict__ W1,
                                                  const float* __restrict__ b1,
                                                  const float* __restrict__ W2,
                                                  const float* __restrict__ b2,
                                                  float* __restrict__ pbuf) {
    __shared__ float e[128];
    __shared__ float t[128];
    int g = blockIdx.x;
    int c = threadIdx.x;
    e[c] = gemb[(size_t)g * 128 + c];
    __syncthreads();
    float acc = b1[c];
#pragma unroll 8
    for (int k = 0; k < 128; ++k) acc += e[k] * W1[k * 128 + c];
    t[c] = fmaxf(acc, 0.f);
    __syncthreads();
    float acc2 = b2[c];
#pragma unroll 8
    for (int k = 0; k < 128; ++k) acc2 += t[k] * W2[k * 128 + c];
    pbuf[(size_t)g * 128 + c] = tanhf(acc2);
}

// ---------------- set-sum + phi head ----------------

__global__ __launch_bounds__(128) void phi_kernel(const float* __restrict__ pbuf,
                                                  const float* __restrict__ W1,
                                                  const float* __restrict__ b1,
                                                  const float* __restrict__ W2,
                                                  const float* __restrict__ b2,
                                                  float* __restrict__ out) {
    __shared__ float a[128];
    __shared__ float u[128];
    int s = blockIdx.x;
    int c = threadIdx.x;
    float acc = 0.f;
#pragma unroll
    for (int p = 0; p < PGS; ++p) acc += pbuf[(size_t)(s + p * SS) * 128 + c];
    a[c] = acc;
    __syncthreads();
    float acc1 = b1[c];
#pragma unroll 8
    for (int k = 0; k < 128; ++k) acc1 += a[k] * W1[k * 128 + c];
    u[c] = fmaxf(acc1, 0.f);
    __syncthreads();
    if (c < CC) {
        float acc2 = b2[c];
#pragma unroll 8
        for (int k = 0; k < 128; ++k) acc2 += u[k] * W2[k * CC + c];
        out[(size_t)s * CC + c] = acc2;
    }
}

// ---------------- launch ----------------

extern "C" void kernel_launch(void* const* d_in, const int* in_sizes, int n_in,
                              void* d_out, int out_size, void* d_ws, size_t ws_size,
                              hipStream_t stream) {
    const float* x   = (const float*)d_in[0];
    const int* ei    = (const int*)d_in[1];
    const float* W1  = (const float*)d_in[4];
    const float* b1  = (const float*)d_in[5];
    const float* W2  = (const float*)d_in[6];
    const float* b2  = (const float*)d_in[7];
    const float* W3  = (const float*)d_in[8];
    const float* b3  = (const float*)d_in[9];
    const float* pW1 = (const float*)d_in[10];
    const float* pb1 = (const float*)d_in[11];
    const float* pW2 = (const float*)d_in[12];
    const float* pb2 = (const float*)d_in[13];
    const float* fW1 = (const float*)d_in[14];
    const float* fb1 = (const float*)d_in[15];
    const float* fW2 = (const float*)d_in[16];
    const float* fb2 = (const float*)d_in[17];
    float* out = (float*)d_out;

    // workspace carve-up (256B aligned)
    char* p = (char*)d_ws;
    auto alloc = [&](size_t bytes) {
        char* r = p;
        p += (bytes + 255) & ~(size_t)255;
        return r;
    };
    int*   degi    = (int*)alloc((size_t)NN * 4);
    float* dinv    = (float*)alloc((size_t)NN * 4);
    int*   row_ptr = (int*)alloc((size_t)(NN + 1) * 4);
    int*   fill    = (int*)alloc((size_t)NN * 4);
    int*   bsum    = (int*)alloc(512 * 4);
    int*   col     = (int*)alloc((size_t)EE * 4);
    float* enorm   = (float*)alloc((size_t)EE * 4);
    float* bufA    = (float*)alloc((size_t)NN * HH * 4);
    float* bufB    = (float*)alloc((size_t)NN * HH * 4);
    float* gemb    = (float*)alloc((size_t)GG * HH * 4);
    float* pbuf    = (float*)alloc((size_t)GG * HH * 4);

    const int nblkN = (NN + 255) / 256;        // 391
    const int nblkE = (EE + 255) / 256;        // 6250

    // CSR build
    zero_int_kernel<<<nblkN, 256, 0, stream>>>(degi, NN);
    count_edges_kernel<<<nblkE, 256, 0, stream>>>(ei + EE, degi, EE);
    scan_chunk_kernel<<<nblkN, 256, 0, stream>>>(degi, row_ptr, bsum, NN);
    scan_bsums_kernel<<<1, 512, 0, stream>>>(bsum, nblkN);
    scan_finish_kernel<<<nblkN, 256, 0, stream>>>(row_ptr, bsum, fill, NN);
    dinv_kernel<<<nblkN, 256, 0, stream>>>(degi, dinv, NN);
    fill_csr_kernel<<<nblkE, 256, 0, stream>>>(ei, row_ptr, fill, dinv, col, enorm, EE);

    const int gemmBlocks = (NN + 63) / 64;     // 1563
    const int aggBlocks  = (NN + 3) / 4;       // 25000

    // layer 1
    gemm128_kernel<<<gemmBlocks, 256, 0, stream>>>(x, W1, bufA, NN);
    aggregate_kernel<<<aggBlocks, 256, 0, stream>>>(bufA, row_ptr, col, enorm, dinv, b1, bufB, NN);
    // layer 2
    gemm128_kernel<<<gemmBlocks, 256, 0, stream>>>(bufB, W2, bufA, NN);
    aggregate_kernel<<<aggBlocks, 256, 0, stream>>>(bufA, row_ptr, col, enorm, dinv, b2, bufB, NN);
    // layer 3
    gemm128_kernel<<<gemmBlocks, 256, 0, stream>>>(bufB, W3, bufA, NN);
    aggregate_kernel<<<aggBlocks, 256, 0, stream>>>(bufA, row_ptr, col, enorm, dinv, b3, bufB, NN);

    // pool -> [G,H]
    pool_kernel<<<(GG + 3) / 4, 256, 0, stream>>>(bufB, gemb);
    // DeepSets
    psi_kernel<<<GG, 128, 0, stream>>>(gemb, pW1, pb1, pW2, pb2, pbuf);
    phi_kernel<<<SS, 128, 0, stream>>>(pbuf, fW1, fb1, fW2, fb2, out);
}

// Round 2
// 793.361 us; speedup vs baseline: 1.3571x; 1.3571x over previous
//
#include <hip/hip_runtime.h>
#include <hip/hip_bf16.h>
#include <math.h>

// Problem constants (match reference)
#define NN 100000
#define EE 1600000
#define HH 128
#define GG 2000
#define SS 200
#define CC 10
#define NPG 50   // nodes per graph
#define PGS 10   // graphs per set

// ---------------- CSR build ----------------

__global__ void zero_int_kernel(int* p, int n) {
    int i = blockIdx.x * 256 + threadIdx.x;
    if (i < n) p[i] = 0;
}

__global__ void count_edges_kernel(const int* __restrict__ dst, int* __restrict__ degi, int e) {
    int i = blockIdx.x * 256 + threadIdx.x;
    if (i < e) atomicAdd(&degi[dst[i]], 1);
}

// per-chunk inclusive scan: row_ptr[i+1] = scan(degi)[i] within chunk; bsum[b] = chunk total
__global__ void scan_chunk_kernel(const int* __restrict__ v, int* __restrict__ row_ptr,
                                  int* __restrict__ bsum, int n) {
    __shared__ int s[256];
    int tid = threadIdx.x;
    int i = blockIdx.x * 256 + tid;
    int x = (i < n) ? v[i] : 0;
    s[tid] = x;
    __syncthreads();
    for (int off = 1; off < 256; off <<= 1) {
        int y = (tid >= off) ? s[tid - off] : 0;
        __syncthreads();
        s[tid] += y;
        __syncthreads();
    }
    if (i < n) row_ptr[i + 1] = s[tid];
    if (tid == 255) bsum[blockIdx.x] = s[255];
}

__global__ void scan_bsums_kernel(int* bsum, int nb) {
    __shared__ int s[512];
    int tid = threadIdx.x;
    int x = (tid < nb) ? bsum[tid] : 0;
    s[tid] = x;
    __syncthreads();
    for (int off = 1; off < 512; off <<= 1) {
        int y = (tid >= off) ? s[tid - off] : 0;
        __syncthreads();
        s[tid] += y;
        __syncthreads();
    }
    if (tid < nb) bsum[tid] = s[tid];
}

__global__ void scan_finish_kernel(int* __restrict__ row_ptr, const int* __restrict__ bsum,
                                   int* __restrict__ fill, int n) {
    int i = blockIdx.x * 256 + threadIdx.x;
    if (i < n) {
        if (blockIdx.x > 0) row_ptr[i + 1] += bsum[blockIdx.x - 1];
        fill[i] = 0;
    }
    if (i == 0) row_ptr[0] = 0;
}

__global__ void dinv_kernel(const int* __restrict__ degi, float* __restrict__ dinv, int n) {
    int i = blockIdx.x * 256 + threadIdx.x;
    if (i < n) dinv[i] = 1.0f / sqrtf((float)(degi[i] + 1));  // +1 self loop
}

// packed edge: {src, norm-as-bits}
__global__ void fill_csr_kernel(const int* __restrict__ ei, const int* __restrict__ rp,
                                int* __restrict__ fill, const float* __restrict__ dinv,
                                int2* __restrict__ epk, int e) {
    int idx = blockIdx.x * 256 + threadIdx.x;
    if (idx >= e) return;
    int s = ei[idx];
    int d = ei[e + idx];
    int pos = atomicAdd(&fill[d], 1);
    int o = rp[d] + pos;
    epk[o] = make_int2(s, __float_as_int(dinv[s] * dinv[d]));
}

// ---------------- GEMM: Y[n][128] = X[n][128] @ W[128][128] ----------------
// 128x128 tile per block, 256 threads, 8x8 register accumulator per thread.
// Xs transposed [k][row] pitch 132 (2-way write conflict, 0-way read conflict
// with rg+16t row interleave). Ws straight copy (broadcast + bank-spread).

#define GPITCH 132

__global__ __launch_bounds__(256) void gemm128_kernel(const float* __restrict__ X,
                                                      const float* __restrict__ W,
                                                      float* __restrict__ Y, int nrows) {
    __shared__ float Ws[128 * 128];     // 64 KB
    __shared__ float Xs[128 * GPITCH];  // 67.6 KB
    int tid = threadIdx.x;
    int row0 = blockIdx.x * 128;
    int nrow = min(128, nrows - row0);

    const float4* W4 = (const float4*)W;
    float4* Ws4 = (float4*)Ws;
#pragma unroll
    for (int i = 0; i < 16; ++i) Ws4[tid + i * 256] = W4[tid + i * 256];

    const float4* X4 = (const float4*)(X + (size_t)row0 * 128);
#pragma unroll
    for (int it = 0; it < 16; ++it) {
        int f = it * 256 + tid;        // float4 index in [0, 128*32)
        int row = f >> 5;
        int k4 = (f & 31) << 2;
        float4 v = make_float4(0.f, 0.f, 0.f, 0.f);
        if (row < nrow) v = X4[f];
        Xs[(k4 + 0) * GPITCH + row] = v.x;
        Xs[(k4 + 1) * GPITCH + row] = v.y;
        Xs[(k4 + 2) * GPITCH + row] = v.z;
        Xs[(k4 + 3) * GPITCH + row] = v.w;
    }
    __syncthreads();

    int rg = tid & 15;   // rows rg + 16t, t in [0,8)
    int cg = tid >> 4;   // cols cg*8 .. cg*8+7
    float acc[8][8];
#pragma unroll
    for (int t = 0; t < 8; ++t)
#pragma unroll
        for (int c = 0; c < 8; ++c) acc[t][c] = 0.f;

#pragma unroll 4
    for (int k = 0; k < 128; ++k) {
        float xv[8];
#pragma unroll
        for (int t = 0; t < 8; ++t) xv[t] = Xs[k * GPITCH + rg + 16 * t];
        float4 wa = Ws4[k * 32 + cg * 2];
        float4 wb = Ws4[k * 32 + cg * 2 + 1];
#pragma unroll
        for (int t = 0; t < 8; ++t) {
            acc[t][0] += xv[t] * wa.x;
            acc[t][1] += xv[t] * wa.y;
            acc[t][2] += xv[t] * wa.z;
            acc[t][3] += xv[t] * wa.w;
            acc[t][4] += xv[t] * wb.x;
            acc[t][5] += xv[t] * wb.y;
            acc[t][6] += xv[t] * wb.z;
            acc[t][7] += xv[t] * wb.w;
        }
    }

#pragma unroll
    for (int t = 0; t < 8; ++t) {
        int row = rg + 16 * t;
        if (row < nrow) {
            float4* Y4 = (float4*)(Y + (size_t)(row0 + row) * 128);
            Y4[cg * 2]     = make_float4(acc[t][0], acc[t][1], acc[t][2], acc[t][3]);
            Y4[cg * 2 + 1] = make_float4(acc[t][4], acc[t][5], acc[t][6], acc[t][7]);
        }
    }
}

// ---------------- GCN aggregation (gather CSR), + bias + relu ----------------
// one wave per node; edge loop unrolled x4 with independent accumulators
// so 4 gathers are in flight per wave.

__global__ __launch_bounds__(256) void aggregate_kernel(const float* __restrict__ hw,
                                                        const int* __restrict__ rp,
                                                        const int2* __restrict__ epk,
                                                        const float* __restrict__ dinv,
                                                        const float* __restrict__ bias,
                                                        float* __restrict__ outp, int n) {
    int wid = threadIdx.x >> 6;
    int lane = threadIdx.x & 63;
    int i = blockIdx.x * 4 + wid;
    if (i >= n) return;
    const float2* hw2 = (const float2*)hw;
    float di = dinv[i];
    float2 self = hw2[(size_t)i * 64 + lane];
    float2 a0, a1, a2, a3;
    a0.x = self.x * di * di; a0.y = self.y * di * di;
    a1 = make_float2(0.f, 0.f);
    a2 = make_float2(0.f, 0.f);
    a3 = make_float2(0.f, 0.f);
    int j0 = rp[i], j1 = rp[i + 1];
    int j = j0;
    for (; j + 4 <= j1; j += 4) {
        int2 e0 = epk[j];
        int2 e1 = epk[j + 1];
        int2 e2 = epk[j + 2];
        int2 e3 = epk[j + 3];
        float2 v0 = hw2[(size_t)e0.x * 64 + lane];
        float2 v1 = hw2[(size_t)e1.x * 64 + lane];
        float2 v2 = hw2[(size_t)e2.x * 64 + lane];
        float2 v3 = hw2[(size_t)e3.x * 64 + lane];
        float w0 = __int_as_float(e0.y);
        float w1 = __int_as_float(e1.y);
        float w2 = __int_as_float(e2.y);
        float w3 = __int_as_float(e3.y);
        a0.x += w0 * v0.x; a0.y += w0 * v0.y;
        a1.x += w1 * v1.x; a1.y += w1 * v1.y;
        a2.x += w2 * v2.x; a2.y += w2 * v2.y;
        a3.x += w3 * v3.x; a3.y += w3 * v3.y;
    }
    for (; j < j1; ++j) {
        int2 e = epk[j];
        float2 v = hw2[(size_t)e.x * 64 + lane];
        float w = __int_as_float(e.y);
        a0.x += w * v.x; a0.y += w * v.y;
    }
    float2 acc;
    acc.x = (a0.x + a1.x) + (a2.x + a3.x);
    acc.y = (a0.y + a1.y) + (a2.y + a3.y);
    float2 bv = ((const float2*)bias)[lane];
    float2 r;
    r.x = fmaxf(acc.x + bv.x, 0.f);
    r.y = fmaxf(acc.y + bv.y, 0.f);
    ((float2*)outp)[(size_t)i * 64 + lane] = r;
}

// ---------------- mean pool (50 consecutive rows per graph) ----------------

__global__ __launch_bounds__(256) void pool_kernel(const float* __restrict__ h,
                                                   float* __restrict__ gemb) {
    int wid = threadIdx.x >> 6;
    int lane = threadIdx.x & 63;
    int g = blockIdx.x * 4 + wid;
    if (g >= GG) return;
    const float2* h2 = (const float2*)h;
    float2 acc = {0.f, 0.f};
    size_t base = (size_t)g * NPG * 64;
    for (int r = 0; r < NPG; ++r) {
        float2 v = h2[base + (size_t)r * 64 + lane];
        acc.x += v.x;
        acc.y += v.y;
    }
    float2 o;
    o.x = acc.x / (float)NPG;
    o.y = acc.y / (float)NPG;
    ((float2*)gemb)[(size_t)g * 64 + lane] = o;
}

// ---------------- DeepSets psi: p_g = tanh(relu(emb W1 + b1) W2 + b2) ----------------

__global__ __launch_bounds__(128) void psi_kernel(const float* __restrict__ gemb,
                                                  const float* __restrict__ W1,
                                                  const float* __restrict__ b1,
                                                  const float* __restrict__ W2,
                                                  const float* __restrict__ b2,
                                                  float* __restrict__ pbuf) {
    __shared__ float e[128];
    __shared__ float t[128];
    int g = blockIdx.x;
    int c = threadIdx.x;
    e[c] = gemb[(size_t)g * 128 + c];
    __syncthreads();
    float acc = b1[c];
#pragma unroll 8
    for (int k = 0; k < 128; ++k) acc += e[k] * W1[k * 128 + c];
    t[c] = fmaxf(acc, 0.f);
    __syncthreads();
    float acc2 = b2[c];
#pragma unroll 8
    for (int k = 0; k < 128; ++k) acc2 += t[k] * W2[k * 128 + c];
    pbuf[(size_t)g * 128 + c] = tanhf(acc2);
}

// ---------------- set-sum + phi head ----------------

__global__ __launch_bounds__(128) void phi_kernel(const float* __restrict__ pbuf,
                                                  const float* __restrict__ W1,
                                                  const float* __restrict__ b1,
                                                  const float* __restrict__ W2,
                                                  const float* __restrict__ b2,
                                                  float* __restrict__ out) {
    __shared__ float a[128];
    __shared__ float u[128];
    int s = blockIdx.x;
    int c = threadIdx.x;
    float acc = 0.f;
#pragma unroll
    for (int p = 0; p < PGS; ++p) acc += pbuf[(size_t)(s + p * SS) * 128 + c];
    a[c] = acc;
    __syncthreads();
    float acc1 = b1[c];
#pragma unroll 8
    for (int k = 0; k < 128; ++k) acc1 += a[k] * W1[k * 128 + c];
    u[c] = fmaxf(acc1, 0.f);
    __syncthreads();
    if (c < CC) {
        float acc2 = b2[c];
#pragma unroll 8
        for (int k = 0; k < 128; ++k) acc2 += u[k] * W2[k * CC + c];
        out[(size_t)s * CC + c] = acc2;
    }
}

// ---------------- launch ----------------

extern "C" void kernel_launch(void* const* d_in, const int* in_sizes, int n_in,
                              void* d_out, int out_size, void* d_ws, size_t ws_size,
                              hipStream_t stream) {
    const float* x   = (const float*)d_in[0];
    const int* ei    = (const int*)d_in[1];
    const float* W1  = (const float*)d_in[4];
    const float* b1  = (const float*)d_in[5];
    const float* W2  = (const float*)d_in[6];
    const float* b2  = (const float*)d_in[7];
    const float* W3  = (const float*)d_in[8];
    const float* b3  = (const float*)d_in[9];
    const float* pW1 = (const float*)d_in[10];
    const float* pb1 = (const float*)d_in[11];
    const float* pW2 = (const float*)d_in[12];
    const float* pb2 = (const float*)d_in[13];
    const float* fW1 = (const float*)d_in[14];
    const float* fb1 = (const float*)d_in[15];
    const float* fW2 = (const float*)d_in[16];
    const float* fb2 = (const float*)d_in[17];
    float* out = (float*)d_out;

    // workspace carve-up (256B aligned)
    char* p = (char*)d_ws;
    auto alloc = [&](size_t bytes) {
        char* r = p;
        p += (bytes + 255) & ~(size_t)255;
        return r;
    };
    int*   degi    = (int*)alloc((size_t)NN * 4);
    float* dinv    = (float*)alloc((size_t)NN * 4);
    int*   row_ptr = (int*)alloc((size_t)(NN + 1) * 4);
    int*   fill    = (int*)alloc((size_t)NN * 4);
    int*   bsum    = (int*)alloc(512 * 4);
    int2*  epk     = (int2*)alloc((size_t)EE * 8);
    float* bufA    = (float*)alloc((size_t)NN * HH * 4);
    float* bufB    = (float*)alloc((size_t)NN * HH * 4);
    float* gemb    = (float*)alloc((size_t)GG * HH * 4);
    float* pbuf    = (float*)alloc((size_t)GG * HH * 4);

    const int nblkN = (NN + 255) / 256;        // 391
    const int nblkE = (EE + 255) / 256;        // 6250

    // CSR build
    zero_int_kernel<<<nblkN, 256, 0, stream>>>(degi, NN);
    count_edges_kernel<<<nblkE, 256, 0, stream>>>(ei + EE, degi, EE);
    scan_chunk_kernel<<<nblkN, 256, 0, stream>>>(degi, row_ptr, bsum, NN);
    scan_bsums_kernel<<<1, 512, 0, stream>>>(bsum, nblkN);
    scan_finish_kernel<<<nblkN, 256, 0, stream>>>(row_ptr, bsum, fill, NN);
    dinv_kernel<<<nblkN, 256, 0, stream>>>(degi, dinv, NN);
    fill_csr_kernel<<<nblkE, 256, 0, stream>>>(ei, row_ptr, fill, dinv, epk, EE);

    const int gemmBlocks = (NN + 127) / 128;   // 782
    const int aggBlocks  = (NN + 3) / 4;       // 25000

    // layer 1
    gemm128_kernel<<<gemmBlocks, 256, 0, stream>>>(x, W1, bufA, NN);
    aggregate_kernel<<<aggBlocks, 256, 0, stream>>>(bufA, row_ptr, epk, dinv, b1, bufB, NN);
    // layer 2
    gemm128_kernel<<<gemmBlocks, 256, 0, stream>>>(bufB, W2, bufA, NN);
    aggregate_kernel<<<aggBlocks, 256, 0, stream>>>(bufA, row_ptr, epk, dinv, b2, bufB, NN);
    // layer 3
    gemm128_kernel<<<gemmBlocks, 256, 0, stream>>>(bufB, W3, bufA, NN);
    aggregate_kernel<<<aggBlocks, 256, 0, stream>>>(bufA, row_ptr, epk, dinv, b3, bufB, NN);

    // pool -> [G,H]
    pool_kernel<<<(GG + 3) / 4, 256, 0, stream>>>(bufB, gemb);
    // DeepSets
    psi_kernel<<<GG, 128, 0, stream>>>(gemb, pW1, pb1, pW2, pb2, pbuf);
    phi_kernel<<<SS, 128, 0, stream>>>(pbuf, fW1, fb1, fW2, fb2, out);
}

// Round 3
// 557.186 us; speedup vs baseline: 1.9324x; 1.4239x over previous
//
#include <hip/hip_runtime.h>
#include <hip/hip_bf16.h>
#include <hip/hip_fp16.h>
#include <math.h>

// Problem constants (match reference)
#define NN 100000
#define EE 1600000
#define HH 128
#define GG 2000
#define SS 200
#define CC 10
#define NPG 50   // nodes per graph
#define PGS 10   // graphs per set

// ---------------- CSR build ----------------

__global__ void zero_int_kernel(int* p, int n) {
    int i = blockIdx.x * 256 + threadIdx.x;
    if (i < n) p[i] = 0;
}

__global__ void count_edges_kernel(const int* __restrict__ dst, int* __restrict__ degi, int e) {
    int i = blockIdx.x * 256 + threadIdx.x;
    if (i < e) atomicAdd(&degi[dst[i]], 1);
}

// per-chunk inclusive scan: row_ptr[i+1] = scan(degi)[i] within chunk; bsum[b] = chunk total
__global__ void scan_chunk_kernel(const int* __restrict__ v, int* __restrict__ row_ptr,
                                  int* __restrict__ bsum, int n) {
    __shared__ int s[256];
    int tid = threadIdx.x;
    int i = blockIdx.x * 256 + tid;
    int x = (i < n) ? v[i] : 0;
    s[tid] = x;
    __syncthreads();
    for (int off = 1; off < 256; off <<= 1) {
        int y = (tid >= off) ? s[tid - off] : 0;
        __syncthreads();
        s[tid] += y;
        __syncthreads();
    }
    if (i < n) row_ptr[i + 1] = s[tid];
    if (tid == 255) bsum[blockIdx.x] = s[255];
}

__global__ void scan_bsums_kernel(int* bsum, int nb) {
    __shared__ int s[512];
    int tid = threadIdx.x;
    int x = (tid < nb) ? bsum[tid] : 0;
    s[tid] = x;
    __syncthreads();
    for (int off = 1; off < 512; off <<= 1) {
        int y = (tid >= off) ? s[tid - off] : 0;
        __syncthreads();
        s[tid] += y;
        __syncthreads();
    }
    if (tid < nb) bsum[tid] = s[tid];
}

__global__ void scan_finish_kernel(int* __restrict__ row_ptr, const int* __restrict__ bsum,
                                   int* __restrict__ fill, int n) {
    int i = blockIdx.x * 256 + threadIdx.x;
    if (i < n) {
        if (blockIdx.x > 0) row_ptr[i + 1] += bsum[blockIdx.x - 1];
        fill[i] = 0;
    }
    if (i == 0) row_ptr[0] = 0;
}

__global__ void dinv_kernel(const int* __restrict__ degi, float* __restrict__ dinv, int n) {
    int i = blockIdx.x * 256 + threadIdx.x;
    if (i < n) dinv[i] = 1.0f / sqrtf((float)(degi[i] + 1));  // +1 self loop
}

// packed edge: {src, norm-as-bits}
__global__ void fill_csr_kernel(const int* __restrict__ ei, const int* __restrict__ rp,
                                int* __restrict__ fill, const float* __restrict__ dinv,
                                int2* __restrict__ epk, int e) {
    int idx = blockIdx.x * 256 + threadIdx.x;
    if (idx >= e) return;
    int s = ei[idx];
    int d = ei[e + idx];
    int pos = atomicAdd(&fill[d], 1);
    int o = rp[d] + pos;
    epk[o] = make_int2(s, __float_as_int(dinv[s] * dinv[d]));
}

// ---------------- GEMM: Y[n][128](fp16) = X[n][128](fp32) @ W[128][128] ----------------
// 128x128 tile per block, 256 threads, 8x8 register accumulator per thread.
// K split into 2 halves of 64 so LDS = 32KB (W half) + 33.8KB (X^T half) -> 2 blocks/CU.

#define GPITCH 132

__global__ __launch_bounds__(256) void gemm128_kernel(const float* __restrict__ X,
                                                      const float* __restrict__ W,
                                                      __half* __restrict__ Y, int nrows) {
    __shared__ float Ws[64 * 128];      // 32 KB (one K-half of W)
    __shared__ float Xs[64 * GPITCH];   // 33.8 KB (one K-half of X, transposed [k][row])
    int tid = threadIdx.x;
    int row0 = blockIdx.x * 128;
    int nrow = min(128, nrows - row0);

    int rg = tid & 15;   // rows rg + 16t, t in [0,8)
    int cg = tid >> 4;   // cols cg*8 .. cg*8+7
    float acc[8][8];
#pragma unroll
    for (int t = 0; t < 8; ++t)
#pragma unroll
        for (int c = 0; c < 8; ++c) acc[t][c] = 0.f;

    const float4* W4 = (const float4*)W;
    const float4* X4 = (const float4*)(X + (size_t)row0 * 128);
    float4* Ws4 = (float4*)Ws;

    for (int kh = 0; kh < 2; ++kh) {
        if (kh) __syncthreads();   // previous compute done before overwriting LDS
        // stage W half: rows kh*64 .. kh*64+63 of W (64x128 floats = 2048 float4)
#pragma unroll
        for (int i = 0; i < 8; ++i) Ws4[tid + i * 256] = W4[kh * 2048 + tid + i * 256];
        // stage X half transposed: 2048 float4 covering [128 rows][16 float4 of this half]
#pragma unroll
        for (int it = 0; it < 8; ++it) {
            int f = it * 256 + tid;          // [0, 2048)
            int row = f >> 4;
            int kk = (f & 15) << 2;          // k within half, 0..60
            float4 v = make_float4(0.f, 0.f, 0.f, 0.f);
            if (row < nrow) v = X4[row * 32 + kh * 16 + (f & 15)];
            Xs[(kk + 0) * GPITCH + row] = v.x;
            Xs[(kk + 1) * GPITCH + row] = v.y;
            Xs[(kk + 2) * GPITCH + row] = v.z;
            Xs[(kk + 3) * GPITCH + row] = v.w;
        }
        __syncthreads();

#pragma unroll 4
        for (int k = 0; k < 64; ++k) {
            float xv[8];
#pragma unroll
            for (int t = 0; t < 8; ++t) xv[t] = Xs[k * GPITCH + rg + 16 * t];
            float4 wa = ((const float4*)Ws)[k * 32 + cg * 2];
            float4 wb = ((const float4*)Ws)[k * 32 + cg * 2 + 1];
#pragma unroll
            for (int t = 0; t < 8; ++t) {
                acc[t][0] += xv[t] * wa.x;
                acc[t][1] += xv[t] * wa.y;
                acc[t][2] += xv[t] * wa.z;
                acc[t][3] += xv[t] * wa.w;
                acc[t][4] += xv[t] * wb.x;
                acc[t][5] += xv[t] * wb.y;
                acc[t][6] += xv[t] * wb.z;
                acc[t][7] += xv[t] * wb.w;
            }
        }
    }

#pragma unroll
    for (int t = 0; t < 8; ++t) {
        int row = rg + 16 * t;
        if (row < nrow) {
            float4 pk;
            __half2* ph = (__half2*)&pk;
            ph[0] = __floats2half2_rn(acc[t][0], acc[t][1]);
            ph[1] = __floats2half2_rn(acc[t][2], acc[t][3]);
            ph[2] = __floats2half2_rn(acc[t][4], acc[t][5]);
            ph[3] = __floats2half2_rn(acc[t][6], acc[t][7]);
            ((float4*)(Y + (size_t)(row0 + row) * 128))[cg] = pk;
        }
    }
}

// ---------------- GCN aggregation (gather CSR, fp16 rows), + bias + relu ----------------
// one wave per node; edge loop unrolled x8 with 4 independent accumulators.

__global__ __launch_bounds__(256) void aggregate_kernel(const __half* __restrict__ hw,
                                                        const int* __restrict__ rp,
                                                        const int2* __restrict__ epk,
                                                        const float* __restrict__ dinv,
                                                        const float* __restrict__ bias,
                                                        float* __restrict__ outp, int n) {
    int wid = threadIdx.x >> 6;
    int lane = threadIdx.x & 63;
    int i = blockIdx.x * 4 + wid;
    if (i >= n) return;
    const __half2* hw2 = (const __half2*)hw;  // row = 64 half2 (256B)
    float di = dinv[i];
    float2 a0, a1, a2, a3;
    {
        float2 self = __half22float2(hw2[(size_t)i * 64 + lane]);
        float w = di * di;
        a0.x = self.x * w; a0.y = self.y * w;
    }
    a1 = make_float2(0.f, 0.f);
    a2 = make_float2(0.f, 0.f);
    a3 = make_float2(0.f, 0.f);
    int j0 = rp[i], j1 = rp[i + 1];
    int j = j0;
    for (; j + 8 <= j1; j += 8) {
        int2 e0 = epk[j + 0];
        int2 e1 = epk[j + 1];
        int2 e2 = epk[j + 2];
        int2 e3 = epk[j + 3];
        int2 e4 = epk[j + 4];
        int2 e5 = epk[j + 5];
        int2 e6 = epk[j + 6];
        int2 e7 = epk[j + 7];
        __half2 v0 = hw2[(size_t)e0.x * 64 + lane];
        __half2 v1 = hw2[(size_t)e1.x * 64 + lane];
        __half2 v2 = hw2[(size_t)e2.x * 64 + lane];
        __half2 v3 = hw2[(size_t)e3.x * 64 + lane];
        __half2 v4 = hw2[(size_t)e4.x * 64 + lane];
        __half2 v5 = hw2[(size_t)e5.x * 64 + lane];
        __half2 v6 = hw2[(size_t)e6.x * 64 + lane];
        __half2 v7 = hw2[(size_t)e7.x * 64 + lane];
        float2 f;
        f = __half22float2(v0); a0.x += __int_as_float(e0.y) * f.x; a0.y += __int_as_float(e0.y) * f.y;
        f = __half22float2(v1); a1.x += __int_as_float(e1.y) * f.x; a1.y += __int_as_float(e1.y) * f.y;
        f = __half22float2(v2); a2.x += __int_as_float(e2.y) * f.x; a2.y += __int_as_float(e2.y) * f.y;
        f = __half22float2(v3); a3.x += __int_as_float(e3.y) * f.x; a3.y += __int_as_float(e3.y) * f.y;
        f = __half22float2(v4); a0.x += __int_as_float(e4.y) * f.x; a0.y += __int_as_float(e4.y) * f.y;
        f = __half22float2(v5); a1.x += __int_as_float(e5.y) * f.x; a1.y += __int_as_float(e5.y) * f.y;
        f = __half22float2(v6); a2.x += __int_as_float(e6.y) * f.x; a2.y += __int_as_float(e6.y) * f.y;
        f = __half22float2(v7); a3.x += __int_as_float(e7.y) * f.x; a3.y += __int_as_float(e7.y) * f.y;
    }
    for (; j + 4 <= j1; j += 4) {
        int2 e0 = epk[j + 0];
        int2 e1 = epk[j + 1];
        int2 e2 = epk[j + 2];
        int2 e3 = epk[j + 3];
        __half2 v0 = hw2[(size_t)e0.x * 64 + lane];
        __half2 v1 = hw2[(size_t)e1.x * 64 + lane];
        __half2 v2 = hw2[(size_t)e2.x * 64 + lane];
        __half2 v3 = hw2[(size_t)e3.x * 64 + lane];
        float2 f;
        f = __half22float2(v0); a0.x += __int_as_float(e0.y) * f.x; a0.y += __int_as_float(e0.y) * f.y;
        f = __half22float2(v1); a1.x += __int_as_float(e1.y) * f.x; a1.y += __int_as_float(e1.y) * f.y;
        f = __half22float2(v2); a2.x += __int_as_float(e2.y) * f.x; a2.y += __int_as_float(e2.y) * f.y;
        f = __half22float2(v3); a3.x += __int_as_float(e3.y) * f.x; a3.y += __int_as_float(e3.y) * f.y;
    }
    for (; j < j1; ++j) {
        int2 e = epk[j];
        __half2 v = hw2[(size_t)e.x * 64 + lane];
        float2 f = __half22float2(v);
        a0.x += __int_as_float(e.y) * f.x; a0.y += __int_as_float(e.y) * f.y;
    }
    float2 acc;
    acc.x = (a0.x + a1.x) + (a2.x + a3.x);
    acc.y = (a0.y + a1.y) + (a2.y + a3.y);
    float2 bv = ((const float2*)bias)[lane];
    float2 r;
    r.x = fmaxf(acc.x + bv.x, 0.f);
    r.y = fmaxf(acc.y + bv.y, 0.f);
    ((float2*)outp)[(size_t)i * 64 + lane] = r;
}

// ---------------- mean pool (50 consecutive rows per graph) ----------------

__global__ __launch_bounds__(256) void pool_kernel(const float* __restrict__ h,
                                                   float* __restrict__ gemb) {
    int wid = threadIdx.x >> 6;
    int lane = threadIdx.x & 63;
    int g = blockIdx.x * 4 + wid;
    if (g >= GG) return;
    const float2* h2 = (const float2*)h;
    float2 acc = {0.f, 0.f};
    size_t base = (size_t)g * NPG * 64;
    for (int r = 0; r < NPG; ++r) {
        float2 v = h2[base + (size_t)r * 64 + lane];
        acc.x += v.x;
        acc.y += v.y;
    }
    float2 o;
    o.x = acc.x / (float)NPG;
    o.y = acc.y / (float)NPG;
    ((float2*)gemb)[(size_t)g * 64 + lane] = o;
}

// ---------------- DeepSets psi: p_g = tanh(relu(emb W1 + b1) W2 + b2) ----------------

__global__ __launch_bounds__(128) void psi_kernel(const float* __restrict__ gemb,
                                                  const float* __restrict__ W1,
                                                  const float* __restrict__ b1,
                                                  const float* __restrict__ W2,
                                                  const float* __restrict__ b2,
                                                  float* __restrict__ pbuf) {
    __shared__ float e[128];
    __shared__ float t[128];
    int g = blockIdx.x;
    int c = threadIdx.x;
    e[c] = gemb[(size_t)g * 128 + c];
    __syncthreads();
    float acc = b1[c];
#pragma unroll 8
    for (int k = 0; k < 128; ++k) acc += e[k] * W1[k * 128 + c];
    t[c] = fmaxf(acc, 0.f);
    __syncthreads();
    float acc2 = b2[c];
#pragma unroll 8
    for (int k = 0; k < 128; ++k) acc2 += t[k] * W2[k * 128 + c];
    pbuf[(size_t)g * 128 + c] = tanhf(acc2);
}

// ---------------- set-sum + phi head ----------------

__global__ __launch_bounds__(128) void phi_kernel(const float* __restrict__ pbuf,
                                                  const float* __restrict__ W1,
                                                  const float* __restrict__ b1,
                                                  const float* __restrict__ W2,
                                                  const float* __restrict__ b2,
                                                  float* __restrict__ out) {
    __shared__ float a[128];
    __shared__ float u[128];
    int s = blockIdx.x;
    int c = threadIdx.x;
    float acc = 0.f;
#pragma unroll
    for (int p = 0; p < PGS; ++p) acc += pbuf[(size_t)(s + p * SS) * 128 + c];
    a[c] = acc;
    __syncthreads();
    float acc1 = b1[c];
#pragma unroll 8
    for (int k = 0; k < 128; ++k) acc1 += a[k] * W1[k * 128 + c];
    u[c] = fmaxf(acc1, 0.f);
    __syncthreads();
    if (c < CC) {
        float acc2 = b2[c];
#pragma unroll 8
        for (int k = 0; k < 128; ++k) acc2 += u[k] * W2[k * CC + c];
        out[(size_t)s * CC + c] = acc2;
    }
}

// ---------------- launch ----------------

extern "C" void kernel_launch(void* const* d_in, const int* in_sizes, int n_in,
                              void* d_out, int out_size, void* d_ws, size_t ws_size,
                              hipStream_t stream) {
    const float* x   = (const float*)d_in[0];
    const int* ei    = (const int*)d_in[1];
    const float* W1  = (const float*)d_in[4];
    const float* b1  = (const float*)d_in[5];
    const float* W2  = (const float*)d_in[6];
    const float* b2  = (const float*)d_in[7];
    const float* W3  = (const float*)d_in[8];
    const float* b3  = (const float*)d_in[9];
    const float* pW1 = (const float*)d_in[10];
    const float* pb1 = (const float*)d_in[11];
    const float* pW2 = (const float*)d_in[12];
    const float* pb2 = (const float*)d_in[13];
    const float* fW1 = (const float*)d_in[14];
    const float* fb1 = (const float*)d_in[15];
    const float* fW2 = (const float*)d_in[16];
    const float* fb2 = (const float*)d_in[17];
    float* out = (float*)d_out;

    // workspace carve-up (256B aligned)
    char* p = (char*)d_ws;
    auto alloc = [&](size_t bytes) {
        char* r = p;
        p += (bytes + 255) & ~(size_t)255;
        return r;
    };
    int*    degi    = (int*)alloc((size_t)NN * 4);
    float*  dinv    = (float*)alloc((size_t)NN * 4);
    int*    row_ptr = (int*)alloc((size_t)(NN + 1) * 4);
    int*    fill    = (int*)alloc((size_t)NN * 4);
    int*    bsum    = (int*)alloc(512 * 4);
    int2*   epk     = (int2*)alloc((size_t)EE * 8);
    __half* bufA    = (__half*)alloc((size_t)NN * HH * 2);   // fp16 gather operand
    float*  bufB    = (float*)alloc((size_t)NN * HH * 4);
    float*  gemb    = (float*)alloc((size_t)GG * HH * 4);
    float*  pbuf    = (float*)alloc((size_t)GG * HH * 4);

    const int nblkN = (NN + 255) / 256;        // 391
    const int nblkE = (EE + 255) / 256;        // 6250

    // CSR build
    zero_int_kernel<<<nblkN, 256, 0, stream>>>(degi, NN);
    count_edges_kernel<<<nblkE, 256, 0, stream>>>(ei + EE, degi, EE);
    scan_chunk_kernel<<<nblkN, 256, 0, stream>>>(degi, row_ptr, bsum, NN);
    scan_bsums_kernel<<<1, 512, 0, stream>>>(bsum, nblkN);
    scan_finish_kernel<<<nblkN, 256, 0, stream>>>(row_ptr, bsum, fill, NN);
    dinv_kernel<<<nblkN, 256, 0, stream>>>(degi, dinv, NN);
    fill_csr_kernel<<<nblkE, 256, 0, stream>>>(ei, row_ptr, fill, dinv, epk, EE);

    const int gemmBlocks = (NN + 127) / 128;   // 782
    const int aggBlocks  = (NN + 3) / 4;       // 25000

    // layer 1
    gemm128_kernel<<<gemmBlocks, 256, 0, stream>>>(x, W1, bufA, NN);
    aggregate_kernel<<<aggBlocks, 256, 0, stream>>>(bufA, row_ptr, epk, dinv, b1, bufB, NN);
    // layer 2
    gemm128_kernel<<<gemmBlocks, 256, 0, stream>>>(bufB, W2, bufA, NN);
    aggregate_kernel<<<aggBlocks, 256, 0, stream>>>(bufA, row_ptr, epk, dinv, b2, bufB, NN);
    // layer 3
    gemm128_kernel<<<gemmBlocks, 256, 0, stream>>>(bufB, W3, bufA, NN);
    aggregate_kernel<<<aggBlocks, 256, 0, stream>>>(bufA, row_ptr, epk, dinv, b3, bufB, NN);

    // pool -> [G,H]
    pool_kernel<<<(GG + 3) / 4, 256, 0, stream>>>(bufB, gemb);
    // DeepSets
    psi_kernel<<<GG, 128, 0, stream>>>(gemb, pW1, pb1, pW2, pb2, pbuf);
    phi_kernel<<<SS, 128, 0, stream>>>(pbuf, fW1, fb1, fW2, fb2, out);
}

// Round 4
// 505.481 us; speedup vs baseline: 2.1301x; 1.1023x over previous
//
#include <hip/hip_runtime.h>
#include <hip/hip_bf16.h>
#include <hip/hip_fp16.h>
#include <math.h>

// Problem constants (match reference)
#define NN 100000
#define EE 1600000
#define HH 128
#define GG 2000
#define SS 200
#define CC 10
#define NPG 50   // nodes per graph
#define PGS 10   // graphs per set

typedef _Float16 f16x8 __attribute__((ext_vector_type(8)));
typedef float    f32x4 __attribute__((ext_vector_type(4)));

// ---------------- CSR build ----------------

__global__ void zero_int_kernel(int* p, int n) {
    int i = blockIdx.x * 256 + threadIdx.x;
    if (i < n) p[i] = 0;
}

__global__ void count_edges_kernel(const int* __restrict__ dst, int* __restrict__ degi, int e) {
    int i = blockIdx.x * 256 + threadIdx.x;
    if (i < e) atomicAdd(&degi[dst[i]], 1);
}

// per-chunk inclusive scan: row_ptr[i+1] = scan(degi)[i] within chunk; bsum[b] = chunk total
__global__ void scan_chunk_kernel(const int* __restrict__ v, int* __restrict__ row_ptr,
                                  int* __restrict__ bsum, int n) {
    __shared__ int s[256];
    int tid = threadIdx.x;
    int i = blockIdx.x * 256 + tid;
    int x = (i < n) ? v[i] : 0;
    s[tid] = x;
    __syncthreads();
    for (int off = 1; off < 256; off <<= 1) {
        int y = (tid >= off) ? s[tid - off] : 0;
        __syncthreads();
        s[tid] += y;
        __syncthreads();
    }
    if (i < n) row_ptr[i + 1] = s[tid];
    if (tid == 255) bsum[blockIdx.x] = s[255];
}

__global__ void scan_bsums_kernel(int* bsum, int nb) {
    __shared__ int s[512];
    int tid = threadIdx.x;
    int x = (tid < nb) ? bsum[tid] : 0;
    s[tid] = x;
    __syncthreads();
    for (int off = 1; off < 512; off <<= 1) {
        int y = (tid >= off) ? s[tid - off] : 0;
        __syncthreads();
        s[tid] += y;
        __syncthreads();
    }
    if (tid < nb) bsum[tid] = s[tid];
}

__global__ void scan_finish_kernel(int* __restrict__ row_ptr, const int* __restrict__ bsum, int n) {
    int i = blockIdx.x * 256 + threadIdx.x;
    if (i < n) {
        if (blockIdx.x > 0) row_ptr[i + 1] += bsum[blockIdx.x - 1];
    }
    if (i == 0) row_ptr[0] = 0;
}

// dinv + cursor init (cursor[i] = row_ptr[i], the exclusive start)
__global__ void dinv_kernel(const int* __restrict__ degi, const int* __restrict__ row_ptr,
                            float* __restrict__ dinv, int* __restrict__ cursor, int n) {
    int i = blockIdx.x * 256 + threadIdx.x;
    if (i < n) {
        dinv[i] = 1.0f / sqrtf((float)(degi[i] + 1));  // +1 self loop
        cursor[i] = row_ptr[i];
    }
}

// scatter src index only (4B) into dst-sorted position
__global__ void fill_csr_kernel(const int* __restrict__ ei, int* __restrict__ cursor,
                                int* __restrict__ col, int e) {
    int idx = blockIdx.x * 256 + threadIdx.x;
    if (idx >= e) return;
    int s = ei[idx];
    int d = ei[e + idx];
    int o = atomicAdd(&cursor[d], 1);
    col[o] = s;
}

// ---------------- MFMA GEMM: Y[n][128](fp16, x dinv[row]) = X[n][128] @ W[128][128] ----------
// 128 rows/block, 4 waves; wave handles 32 rows (2 row-tiles of 16), 8 col-tiles, K=4x32.
// Wt: W transposed fp16 in LDS (pitch 136 halves -> 2-way-free b128 reads).
// Epilogue: stage fp16 output in LDS, write back fully coalesced 16B/lane.

#define WTP 136

template <bool IN32>
__global__ __launch_bounds__(256) void gemm_mfma_kernel(const void* __restrict__ Xv,
                                                        const float* __restrict__ W,
                                                        const float* __restrict__ dinv,
                                                        _Float16* __restrict__ Y, int nrows) {
    __shared__ _Float16 Wt[128][WTP];   // 34.8 KB
    __shared__ _Float16 Ob[128][WTP];   // 34.8 KB
    int tid = threadIdx.x;
    int row0 = blockIdx.x * 128;

    // stage W transposed as fp16
    const float4* W4 = (const float4*)W;
#pragma unroll
    for (int it = 0; it < 16; ++it) {
        int f = it * 256 + tid;      // float4 id in [0,4096)
        int k = f >> 5;              // W row
        int c = (f & 31) << 2;       // W col (x4)
        float4 v = W4[f];
        Wt[c + 0][k] = (_Float16)v.x;
        Wt[c + 1][k] = (_Float16)v.y;
        Wt[c + 2][k] = (_Float16)v.z;
        Wt[c + 3][k] = (_Float16)v.w;
    }
    __syncthreads();

    int wave = tid >> 6;
    int l = tid & 63;
    int arow = l & 15;
    int kg = l >> 4;                 // k-group 0..3
    int baseRow = row0 + wave * 32;

    // A fragments: lane holds X[row][ks*32 + kg*8 .. +8]
    f16x8 afrag[2][4];
#pragma unroll
    for (int rt = 0; rt < 2; ++rt) {
        int r = baseRow + rt * 16 + arow;
        r = min(r, nrows - 1);
        if (IN32) {
            const float* xr = ((const float*)Xv) + (size_t)r * 128;
#pragma unroll
            for (int ks = 0; ks < 4; ++ks) {
                int k0 = ks * 32 + kg * 8;
                float4 a = ((const float4*)xr)[k0 >> 2];
                float4 b = ((const float4*)xr)[(k0 >> 2) + 1];
                f16x8 v;
                v[0] = (_Float16)a.x; v[1] = (_Float16)a.y;
                v[2] = (_Float16)a.z; v[3] = (_Float16)a.w;
                v[4] = (_Float16)b.x; v[5] = (_Float16)b.y;
                v[6] = (_Float16)b.z; v[7] = (_Float16)b.w;
                afrag[rt][ks] = v;
            }
        } else {
            const f16x8* xr = (const f16x8*)(((const _Float16*)Xv) + (size_t)r * 128);
#pragma unroll
            for (int ks = 0; ks < 4; ++ks) afrag[rt][ks] = xr[ks * 4 + kg];
        }
    }

    f32x4 acc[2][8];
#pragma unroll
    for (int rt = 0; rt < 2; ++rt)
#pragma unroll
        for (int ct = 0; ct < 8; ++ct) acc[rt][ct] = (f32x4){0.f, 0.f, 0.f, 0.f};

#pragma unroll
    for (int ct = 0; ct < 8; ++ct) {
#pragma unroll
        for (int ks = 0; ks < 4; ++ks) {
            f16x8 b = *(const f16x8*)&Wt[ct * 16 + arow][ks * 32 + kg * 8];
            acc[0][ct] = __builtin_amdgcn_mfma_f32_16x16x32_f16(afrag[0][ks], b, acc[0][ct], 0, 0, 0);
            acc[1][ct] = __builtin_amdgcn_mfma_f32_16x16x32_f16(afrag[1][ks], b, acc[1][ct], 0, 0, 0);
        }
    }

    // dinv for the 8 rows this lane owns (D: row = rt*16 + 4*kg + j, col = arow)
    float dv[2][4];
#pragma unroll
    for (int rt = 0; rt < 2; ++rt)
#pragma unroll
        for (int j = 0; j < 4; ++j) {
            int r = baseRow + rt * 16 + 4 * kg + j;
            dv[rt][j] = dinv[min(r, nrows - 1)];
        }

    // stage to LDS (own wave's 32 rows only — no block sync needed)
#pragma unroll
    for (int rt = 0; rt < 2; ++rt)
#pragma unroll
        for (int ct = 0; ct < 8; ++ct)
#pragma unroll
            for (int j = 0; j < 4; ++j)
                Ob[wave * 32 + rt * 16 + 4 * kg + j][ct * 16 + arow] =
                    (_Float16)(acc[rt][ct][j] * dv[rt][j]);

    // coalesced write-back: 8 x 16B per lane
#pragma unroll
    for (int i = 0; i < 8; ++i) {
        int q = i * 64 + l;          // [0,512): 32 rows x 16 chunks
        int lrow = q >> 4;
        int c = q & 15;
        int r = baseRow + lrow;
        if (r < nrows) {
            f16x8 v = *(const f16x8*)&Ob[wave * 32 + lrow][c * 8];
            *(f16x8*)(Y + (size_t)r * 128 + c * 8) = v;
        }
    }
}

// ---------------- GCN aggregation: out = relu(dinv[i]*(sum hw'[col] + hw'[i]) + b), fp16 out --

__global__ __launch_bounds__(256) void aggregate_kernel(const __half* __restrict__ hw,
                                                        const int* __restrict__ rp,
                                                        const int* __restrict__ col,
                                                        const float* __restrict__ dinv,
                                                        const float* __restrict__ bias,
                                                        __half* __restrict__ outp, int n) {
    int wid = threadIdx.x >> 6;
    int lane = threadIdx.x & 63;
    int i = blockIdx.x * 4 + wid;
    if (i >= n) return;
    const __half2* hw2 = (const __half2*)hw;  // row = 64 half2 (256B)
    float2 a0, a1, a2, a3;
    {
        float2 self = __half22float2(hw2[(size_t)i * 64 + lane]);
        a0.x = self.x; a0.y = self.y;
    }
    a1 = make_float2(0.f, 0.f);
    a2 = make_float2(0.f, 0.f);
    a3 = make_float2(0.f, 0.f);
    int j0 = rp[i], j1 = rp[i + 1];
    int j = j0;
    for (; j + 8 <= j1; j += 8) {
        int s0 = col[j + 0];
        int s1 = col[j + 1];
        int s2 = col[j + 2];
        int s3 = col[j + 3];
        int s4 = col[j + 4];
        int s5 = col[j + 5];
        int s6 = col[j + 6];
        int s7 = col[j + 7];
        __half2 v0 = hw2[(size_t)s0 * 64 + lane];
        __half2 v1 = hw2[(size_t)s1 * 64 + lane];
        __half2 v2 = hw2[(size_t)s2 * 64 + lane];
        __half2 v3 = hw2[(size_t)s3 * 64 + lane];
        __half2 v4 = hw2[(size_t)s4 * 64 + lane];
        __half2 v5 = hw2[(size_t)s5 * 64 + lane];
        __half2 v6 = hw2[(size_t)s6 * 64 + lane];
        __half2 v7 = hw2[(size_t)s7 * 64 + lane];
        float2 f;
        f = __half22float2(v0); a0.x += f.x; a0.y += f.y;
        f = __half22float2(v1); a1.x += f.x; a1.y += f.y;
        f = __half22float2(v2); a2.x += f.x; a2.y += f.y;
        f = __half22float2(v3); a3.x += f.x; a3.y += f.y;
        f = __half22float2(v4); a0.x += f.x; a0.y += f.y;
        f = __half22float2(v5); a1.x += f.x; a1.y += f.y;
        f = __half22float2(v6); a2.x += f.x; a2.y += f.y;
        f = __half22float2(v7); a3.x += f.x; a3.y += f.y;
    }
    for (; j + 4 <= j1; j += 4) {
        int s0 = col[j + 0];
        int s1 = col[j + 1];
        int s2 = col[j + 2];
        int s3 = col[j + 3];
        __half2 v0 = hw2[(size_t)s0 * 64 + lane];
        __half2 v1 = hw2[(size_t)s1 * 64 + lane];
        __half2 v2 = hw2[(size_t)s2 * 64 + lane];
        __half2 v3 = hw2[(size_t)s3 * 64 + lane];
        float2 f;
        f = __half22float2(v0); a0.x += f.x; a0.y += f.y;
        f = __half22float2(v1); a1.x += f.x; a1.y += f.y;
        f = __half22float2(v2); a2.x += f.x; a2.y += f.y;
        f = __half22float2(v3); a3.x += f.x; a3.y += f.y;
    }
    for (; j < j1; ++j) {
        int s = col[j];
        float2 f = __half22float2(hw2[(size_t)s * 64 + lane]);
        a0.x += f.x; a0.y += f.y;
    }
    float di = dinv[i];
    float2 acc;
    acc.x = ((a0.x + a1.x) + (a2.x + a3.x)) * di;
    acc.y = ((a0.y + a1.y) + (a2.y + a3.y)) * di;
    float2 bv = ((const float2*)bias)[lane];
    float rx = fmaxf(acc.x + bv.x, 0.f);
    float ry = fmaxf(acc.y + bv.y, 0.f);
    ((__half2*)outp)[(size_t)i * 64 + lane] = __floats2half2_rn(rx, ry);
}

// ---------------- mean pool (50 consecutive fp16 rows per graph) ----------------

__global__ __launch_bounds__(256) void pool_kernel(const __half* __restrict__ h,
                                                   float* __restrict__ gemb) {
    int wid = threadIdx.x >> 6;
    int lane = threadIdx.x & 63;
    int g = blockIdx.x * 4 + wid;
    if (g >= GG) return;
    const __half2* h2 = (const __half2*)h;
    float2 acc = {0.f, 0.f};
    size_t base = (size_t)g * NPG * 64;
    for (int r = 0; r < NPG; ++r) {
        float2 v = __half22float2(h2[base + (size_t)r * 64 + lane]);
        acc.x += v.x;
        acc.y += v.y;
    }
    float2 o;
    o.x = acc.x / (float)NPG;
    o.y = acc.y / (float)NPG;
    ((float2*)gemb)[(size_t)g * 64 + lane] = o;
}

// ---------------- DeepSets psi: p_g = tanh(relu(emb W1 + b1) W2 + b2) ----------------

__global__ __launch_bounds__(128) void psi_kernel(const float* __restrict__ gemb,
                                                  const float* __restrict__ W1,
                                                  const float* __restrict__ b1,
                                                  const float* __restrict__ W2,
                                                  const float* __restrict__ b2,
                                                  float* __restrict__ pbuf) {
    __shared__ float e[128];
    __shared__ float t[128];
    int g = blockIdx.x;
    int c = threadIdx.x;
    e[c] = gemb[(size_t)g * 128 + c];
    __syncthreads();
    float acc = b1[c];
#pragma unroll 8
    for (int k = 0; k < 128; ++k) acc += e[k] * W1[k * 128 + c];
    t[c] = fmaxf(acc, 0.f);
    __syncthreads();
    float acc2 = b2[c];
#pragma unroll 8
    for (int k = 0; k < 128; ++k) acc2 += t[k] * W2[k * 128 + c];
    pbuf[(size_t)g * 128 + c] = tanhf(acc2);
}

// ---------------- set-sum + phi head ----------------

__global__ __launch_bounds__(128) void phi_kernel(const float* __restrict__ pbuf,
                                                  const float* __restrict__ W1,
                                                  const float* __restrict__ b1,
                                                  const float* __restrict__ W2,
                                                  const float* __restrict__ b2,
                                                  float* __restrict__ out) {
    __shared__ float a[128];
    __shared__ float u[128];
    int s = blockIdx.x;
    int c = threadIdx.x;
    float acc = 0.f;
#pragma unroll
    for (int p = 0; p < PGS; ++p) acc += pbuf[(size_t)(s + p * SS) * 128 + c];
    a[c] = acc;
    __syncthreads();
    float acc1 = b1[c];
#pragma unroll 8
    for (int k = 0; k < 128; ++k) acc1 += a[k] * W1[k * 128 + c];
    u[c] = fmaxf(acc1, 0.f);
    __syncthreads();
    if (c < CC) {
        float acc2 = b2[c];
#pragma unroll 8
        for (int k = 0; k < 128; ++k) acc2 += u[k] * W2[k * CC + c];
        out[(size_t)s * CC + c] = acc2;
    }
}

// ---------------- launch ----------------

extern "C" void kernel_launch(void* const* d_in, const int* in_sizes, int n_in,
                              void* d_out, int out_size, void* d_ws, size_t ws_size,
                              hipStream_t stream) {
    const float* x   = (const float*)d_in[0];
    const int* ei    = (const int*)d_in[1];
    const float* W1  = (const float*)d_in[4];
    const float* b1  = (const float*)d_in[5];
    const float* W2  = (const float*)d_in[6];
    const float* b2  = (const float*)d_in[7];
    const float* W3  = (const float*)d_in[8];
    const float* b3  = (const float*)d_in[9];
    const float* pW1 = (const float*)d_in[10];
    const float* pb1 = (const float*)d_in[11];
    const float* pW2 = (const float*)d_in[12];
    const float* pb2 = (const float*)d_in[13];
    const float* fW1 = (const float*)d_in[14];
    const float* fb1 = (const float*)d_in[15];
    const float* fW2 = (const float*)d_in[16];
    const float* fb2 = (const float*)d_in[17];
    float* out = (float*)d_out;

    // workspace carve-up (256B aligned)
    char* p = (char*)d_ws;
    auto alloc = [&](size_t bytes) {
        char* r = p;
        p += (bytes + 255) & ~(size_t)255;
        return r;
    };
    int*      degi    = (int*)alloc((size_t)NN * 4);
    float*    dinv    = (float*)alloc((size_t)NN * 4);
    int*      row_ptr = (int*)alloc((size_t)(NN + 1) * 4);
    int*      cursor  = (int*)alloc((size_t)NN * 4);
    int*      bsum    = (int*)alloc(512 * 4);
    int*      col     = (int*)alloc((size_t)EE * 4);
    _Float16* bufA    = (_Float16*)alloc((size_t)NN * HH * 2);  // dinv-scaled XW (gather operand)
    __half*   bufB    = (__half*)alloc((size_t)NN * HH * 2);    // relu'd layer output
    float*    gemb    = (float*)alloc((size_t)GG * HH * 4);
    float*    pbuf    = (float*)alloc((size_t)GG * HH * 4);

    const int nblkN = (NN + 255) / 256;        // 391
    const int nblkE = (EE + 255) / 256;        // 6250

    // CSR build
    zero_int_kernel<<<nblkN, 256, 0, stream>>>(degi, NN);
    count_edges_kernel<<<nblkE, 256, 0, stream>>>(ei + EE, degi, EE);
    scan_chunk_kernel<<<nblkN, 256, 0, stream>>>(degi, row_ptr, bsum, NN);
    scan_bsums_kernel<<<1, 512, 0, stream>>>(bsum, nblkN);
    scan_finish_kernel<<<nblkN, 256, 0, stream>>>(row_ptr, bsum, NN);
    dinv_kernel<<<nblkN, 256, 0, stream>>>(degi, row_ptr, dinv, cursor, NN);
    fill_csr_kernel<<<nblkE, 256, 0, stream>>>(ei, cursor, col, EE);

    const int gemmBlocks = (NN + 127) / 128;   // 782
    const int aggBlocks  = (NN + 3) / 4;       // 25000

    // layer 1
    gemm_mfma_kernel<true><<<gemmBlocks, 256, 0, stream>>>(x, W1, dinv, bufA, NN);
    aggregate_kernel<<<aggBlocks, 256, 0, stream>>>((const __half*)bufA, row_ptr, col, dinv, b1, bufB, NN);
    // layer 2
    gemm_mfma_kernel<false><<<gemmBlocks, 256, 0, stream>>>(bufB, W2, dinv, bufA, NN);
    aggregate_kernel<<<aggBlocks, 256, 0, stream>>>((const __half*)bufA, row_ptr, col, dinv, b2, bufB, NN);
    // layer 3
    gemm_mfma_kernel<false><<<gemmBlocks, 256, 0, stream>>>(bufB, W3, dinv, bufA, NN);
    aggregate_kernel<<<aggBlocks, 256, 0, stream>>>((const __half*)bufA, row_ptr, col, dinv, b3, bufB, NN);

    // pool -> [G,H]
    pool_kernel<<<(GG + 3) / 4, 256, 0, stream>>>(bufB, gemb);
    // DeepSets
    psi_kernel<<<GG, 128, 0, stream>>>(gemb, pW1, pb1, pW2, pb2, pbuf);
    phi_kernel<<<SS, 128, 0, stream>>>(pbuf, fW1, fb1, fW2, fb2, out);
}

// Round 5
// 448.925 us; speedup vs baseline: 2.3984x; 1.1260x over previous
//
#include <hip/hip_runtime.h>
#include <hip/hip_bf16.h>
#include <hip/hip_fp16.h>
#include <math.h>

// Problem constants (match reference)
#define NN 100000
#define EE 1600000
#define HH 128
#define GG 2000
#define SS 200
#define CC 10
#define NPG 50   // nodes per graph
#define PGS 10   // graphs per set
#define NCLS 8             // XCD classes for scatter partitioning
#define CLSW 12500         // dst range width per class (100000/8)

typedef _Float16 f16x8 __attribute__((ext_vector_type(8)));
typedef float    f32x4 __attribute__((ext_vector_type(4)));

// ---------------- CSR build ----------------

__global__ void zero_int_kernel(int* p, int n) {
    int i = blockIdx.x * 256 + threadIdx.x;
    if (i < n) p[i] = 0;
}

__global__ void count_edges_kernel(const int* __restrict__ dst, int* __restrict__ degi, int e) {
    int i = blockIdx.x * 256 + threadIdx.x;
    if (i < e) atomicAdd(&degi[dst[i]], 1);
}

// per-chunk inclusive scan: row_ptr[i+1] = scan(degi)[i] within chunk; bsum[b] = chunk total
__global__ void scan_chunk_kernel(const int* __restrict__ v, int* __restrict__ row_ptr,
                                  int* __restrict__ bsum, int n) {
    __shared__ int s[256];
    int tid = threadIdx.x;
    int i = blockIdx.x * 256 + tid;
    int x = (i < n) ? v[i] : 0;
    s[tid] = x;
    __syncthreads();
    for (int off = 1; off < 256; off <<= 1) {
        int y = (tid >= off) ? s[tid - off] : 0;
        __syncthreads();
        s[tid] += y;
        __syncthreads();
    }
    if (i < n) row_ptr[i + 1] = s[tid];
    if (tid == 255) bsum[blockIdx.x] = s[255];
}

__global__ void scan_bsums_kernel(int* bsum, int nb) {
    __shared__ int s[512];
    int tid = threadIdx.x;
    int x = (tid < nb) ? bsum[tid] : 0;
    s[tid] = x;
    __syncthreads();
    for (int off = 1; off < 512; off <<= 1) {
        int y = (tid >= off) ? s[tid - off] : 0;
        __syncthreads();
        s[tid] += y;
        __syncthreads();
    }
    if (tid < nb) bsum[tid] = s[tid];
}

__global__ void scan_finish_kernel(int* __restrict__ row_ptr, const int* __restrict__ bsum, int n) {
    int i = blockIdx.x * 256 + threadIdx.x;
    if (i < n) {
        if (blockIdx.x > 0) row_ptr[i + 1] += bsum[blockIdx.x - 1];
    }
    if (i == 0) row_ptr[0] = 0;
}

// dinv + cursor init (cursor[i] = row_ptr[i], the exclusive start)
__global__ void dinv_kernel(const int* __restrict__ degi, const int* __restrict__ row_ptr,
                            float* __restrict__ dinv, int* __restrict__ cursor, int n) {
    int i = blockIdx.x * 256 + threadIdx.x;
    if (i < n) {
        dinv[i] = 1.0f / sqrtf((float)(degi[i] + 1));  // +1 self loop
        cursor[i] = row_ptr[i];
    }
}

// class-partitioned scatter: block handles edge chunk (bid>>3) and dst class (bid&7).
// All writes/atomics for a given dst range come from one block-class (-> one XCD),
// eliminating cross-XCD cache-line ping-pong on the CSR fill.
__global__ __launch_bounds__(256) void fill_csr_kernel(const int* __restrict__ ei,
                                                       int* __restrict__ cursor,
                                                       int* __restrict__ col, int e) {
    int cls = blockIdx.x & (NCLS - 1);
    int idx = (blockIdx.x >> 3) * 256 + threadIdx.x;
    if (idx >= e) return;
    int d = ei[e + idx];
    if ((unsigned)d / CLSW == (unsigned)cls) {
        int s = ei[idx];
        int o = atomicAdd(&cursor[d], 1);
        col[o] = s;
    }
}

// ---------------- MFMA GEMM: Y[n][128](fp16, x dinv[row]) = X[n][128] @ W[128][128] ----------
// 128 rows/block, 4 waves; wave handles 32 rows (2 row-tiles of 16), 8 col-tiles, K=4x32.
// Wt: W transposed fp16 in LDS (pitch 136 halves -> 2-way-free b128 reads).
// Epilogue: stage fp16 output in LDS, write back fully coalesced 16B/lane.

#define WTP 136

template <bool IN32>
__global__ __launch_bounds__(256) void gemm_mfma_kernel(const void* __restrict__ Xv,
                                                        const float* __restrict__ W,
                                                        const float* __restrict__ dinv,
                                                        _Float16* __restrict__ Y, int nrows) {
    __shared__ _Float16 Wt[128][WTP];   // 34.8 KB
    __shared__ _Float16 Ob[128][WTP];   // 34.8 KB
    int tid = threadIdx.x;
    int row0 = blockIdx.x * 128;

    // stage W transposed as fp16
    const float4* W4 = (const float4*)W;
#pragma unroll
    for (int it = 0; it < 16; ++it) {
        int f = it * 256 + tid;      // float4 id in [0,4096)
        int k = f >> 5;              // W row
        int c = (f & 31) << 2;       // W col (x4)
        float4 v = W4[f];
        Wt[c + 0][k] = (_Float16)v.x;
        Wt[c + 1][k] = (_Float16)v.y;
        Wt[c + 2][k] = (_Float16)v.z;
        Wt[c + 3][k] = (_Float16)v.w;
    }
    __syncthreads();

    int wave = tid >> 6;
    int l = tid & 63;
    int arow = l & 15;
    int kg = l >> 4;                 // k-group 0..3
    int baseRow = row0 + wave * 32;

    // A fragments: lane holds X[row][ks*32 + kg*8 .. +8]
    f16x8 afrag[2][4];
#pragma unroll
    for (int rt = 0; rt < 2; ++rt) {
        int r = baseRow + rt * 16 + arow;
        r = min(r, nrows - 1);
        if (IN32) {
            const float* xr = ((const float*)Xv) + (size_t)r * 128;
#pragma unroll
            for (int ks = 0; ks < 4; ++ks) {
                int k0 = ks * 32 + kg * 8;
                float4 a = ((const float4*)xr)[k0 >> 2];
                float4 b = ((const float4*)xr)[(k0 >> 2) + 1];
                f16x8 v;
                v[0] = (_Float16)a.x; v[1] = (_Float16)a.y;
                v[2] = (_Float16)a.z; v[3] = (_Float16)a.w;
                v[4] = (_Float16)b.x; v[5] = (_Float16)b.y;
                v[6] = (_Float16)b.z; v[7] = (_Float16)b.w;
                afrag[rt][ks] = v;
            }
        } else {
            const f16x8* xr = (const f16x8*)(((const _Float16*)Xv) + (size_t)r * 128);
#pragma unroll
            for (int ks = 0; ks < 4; ++ks) afrag[rt][ks] = xr[ks * 4 + kg];
        }
    }

    f32x4 acc[2][8];
#pragma unroll
    for (int rt = 0; rt < 2; ++rt)
#pragma unroll
        for (int ct = 0; ct < 8; ++ct) acc[rt][ct] = (f32x4){0.f, 0.f, 0.f, 0.f};

#pragma unroll
    for (int ct = 0; ct < 8; ++ct) {
#pragma unroll
        for (int ks = 0; ks < 4; ++ks) {
            f16x8 b = *(const f16x8*)&Wt[ct * 16 + arow][ks * 32 + kg * 8];
            acc[0][ct] = __builtin_amdgcn_mfma_f32_16x16x32_f16(afrag[0][ks], b, acc[0][ct], 0, 0, 0);
            acc[1][ct] = __builtin_amdgcn_mfma_f32_16x16x32_f16(afrag[1][ks], b, acc[1][ct], 0, 0, 0);
        }
    }

    // dinv for the 8 rows this lane owns (D: row = rt*16 + 4*kg + j, col = arow)
    float dv[2][4];
#pragma unroll
    for (int rt = 0; rt < 2; ++rt)
#pragma unroll
        for (int j = 0; j < 4; ++j) {
            int r = baseRow + rt * 16 + 4 * kg + j;
            dv[rt][j] = dinv[min(r, nrows - 1)];
        }

    // stage to LDS (own wave's 32 rows only — no block sync needed)
#pragma unroll
    for (int rt = 0; rt < 2; ++rt)
#pragma unroll
        for (int ct = 0; ct < 8; ++ct)
#pragma unroll
            for (int j = 0; j < 4; ++j)
                Ob[wave * 32 + rt * 16 + 4 * kg + j][ct * 16 + arow] =
                    (_Float16)(acc[rt][ct][j] * dv[rt][j]);

    // coalesced write-back: 8 x 16B per lane
#pragma unroll
    for (int i = 0; i < 8; ++i) {
        int q = i * 64 + l;          // [0,512): 32 rows x 16 chunks
        int lrow = q >> 4;
        int c = q & 15;
        int r = baseRow + lrow;
        if (r < nrows) {
            f16x8 v = *(const f16x8*)&Ob[wave * 32 + lrow][c * 8];
            *(f16x8*)(Y + (size_t)r * 128 + c * 8) = v;
        }
    }
}

// ---------------- GCN aggregation: out = relu(dinv[i]*(sum hw'[col] + hw'[i]) + b), fp16 out --

__global__ __launch_bounds__(256) void aggregate_kernel(const __half* __restrict__ hw,
                                                        const int* __restrict__ rp,
                                                        const int* __restrict__ col,
                                                        const float* __restrict__ dinv,
                                                        const float* __restrict__ bias,
                                                        __half* __restrict__ outp, int n) {
    int wid = threadIdx.x >> 6;
    int lane = threadIdx.x & 63;
    int i = blockIdx.x * 4 + wid;
    if (i >= n) return;
    const __half2* hw2 = (const __half2*)hw;  // row = 64 half2 (256B)
    float2 a0, a1, a2, a3;
    {
        float2 self = __half22float2(hw2[(size_t)i * 64 + lane]);
        a0.x = self.x; a0.y = self.y;
    }
    a1 = make_float2(0.f, 0.f);
    a2 = make_float2(0.f, 0.f);
    a3 = make_float2(0.f, 0.f);
    int j0 = rp[i], j1 = rp[i + 1];
    int j = j0;
    for (; j + 8 <= j1; j += 8) {
        int s0 = col[j + 0];
        int s1 = col[j + 1];
        int s2 = col[j + 2];
        int s3 = col[j + 3];
        int s4 = col[j + 4];
        int s5 = col[j + 5];
        int s6 = col[j + 6];
        int s7 = col[j + 7];
        __half2 v0 = hw2[(size_t)s0 * 64 + lane];
        __half2 v1 = hw2[(size_t)s1 * 64 + lane];
        __half2 v2 = hw2[(size_t)s2 * 64 + lane];
        __half2 v3 = hw2[(size_t)s3 * 64 + lane];
        __half2 v4 = hw2[(size_t)s4 * 64 + lane];
        __half2 v5 = hw2[(size_t)s5 * 64 + lane];
        __half2 v6 = hw2[(size_t)s6 * 64 + lane];
        __half2 v7 = hw2[(size_t)s7 * 64 + lane];
        float2 f;
        f = __half22float2(v0); a0.x += f.x; a0.y += f.y;
        f = __half22float2(v1); a1.x += f.x; a1.y += f.y;
        f = __half22float2(v2); a2.x += f.x; a2.y += f.y;
        f = __half22float2(v3); a3.x += f.x; a3.y += f.y;
        f = __half22float2(v4); a0.x += f.x; a0.y += f.y;
        f = __half22float2(v5); a1.x += f.x; a1.y += f.y;
        f = __half22float2(v6); a2.x += f.x; a2.y += f.y;
        f = __half22float2(v7); a3.x += f.x; a3.y += f.y;
    }
    for (; j + 4 <= j1; j += 4) {
        int s0 = col[j + 0];
        int s1 = col[j + 1];
        int s2 = col[j + 2];
        int s3 = col[j + 3];
        __half2 v0 = hw2[(size_t)s0 * 64 + lane];
        __half2 v1 = hw2[(size_t)s1 * 64 + lane];
        __half2 v2 = hw2[(size_t)s2 * 64 + lane];
        __half2 v3 = hw2[(size_t)s3 * 64 + lane];
        float2 f;
        f = __half22float2(v0); a0.x += f.x; a0.y += f.y;
        f = __half22float2(v1); a1.x += f.x; a1.y += f.y;
        f = __half22float2(v2); a2.x += f.x; a2.y += f.y;
        f = __half22float2(v3); a3.x += f.x; a3.y += f.y;
    }
    for (; j < j1; ++j) {
        int s = col[j];
        float2 f = __half22float2(hw2[(size_t)s * 64 + lane]);
        a0.x += f.x; a0.y += f.y;
    }
    float di = dinv[i];
    float2 acc;
    acc.x = ((a0.x + a1.x) + (a2.x + a3.x)) * di;
    acc.y = ((a0.y + a1.y) + (a2.y + a3.y)) * di;
    float2 bv = ((const float2*)bias)[lane];
    float rx = fmaxf(acc.x + bv.x, 0.f);
    float ry = fmaxf(acc.y + bv.y, 0.f);
    ((__half2*)outp)[(size_t)i * 64 + lane] = __floats2half2_rn(rx, ry);
}

// ---------------- mean pool (50 consecutive fp16 rows per graph) ----------------

__global__ __launch_bounds__(256) void pool_kernel(const __half* __restrict__ h,
                                                   float* __restrict__ gemb) {
    int wid = threadIdx.x >> 6;
    int lane = threadIdx.x & 63;
    int g = blockIdx.x * 4 + wid;
    if (g >= GG) return;
    const __half2* h2 = (const __half2*)h;
    float2 acc = {0.f, 0.f};
    size_t base = (size_t)g * NPG * 64;
    for (int r = 0; r < NPG; ++r) {
        float2 v = __half22float2(h2[base + (size_t)r * 64 + lane]);
        acc.x += v.x;
        acc.y += v.y;
    }
    float2 o;
    o.x = acc.x / (float)NPG;
    o.y = acc.y / (float)NPG;
    ((float2*)gemb)[(size_t)g * 64 + lane] = o;
}

// ---------------- DeepSets psi: p_g = tanh(relu(emb W1 + b1) W2 + b2) ----------------

__global__ __launch_bounds__(128) void psi_kernel(const float* __restrict__ gemb,
                                                  const float* __restrict__ W1,
                                                  const float* __restrict__ b1,
                                                  const float* __restrict__ W2,
                                                  const float* __restrict__ b2,
                                                  float* __restrict__ pbuf) {
    __shared__ float e[128];
    __shared__ float t[128];
    int g = blockIdx.x;
    int c = threadIdx.x;
    e[c] = gemb[(size_t)g * 128 + c];
    __syncthreads();
    float acc = b1[c];
#pragma unroll 8
    for (int k = 0; k < 128; ++k) acc += e[k] * W1[k * 128 + c];
    t[c] = fmaxf(acc, 0.f);
    __syncthreads();
    float acc2 = b2[c];
#pragma unroll 8
    for (int k = 0; k < 128; ++k) acc2 += t[k] * W2[k * 128 + c];
    pbuf[(size_t)g * 128 + c] = tanhf(acc2);
}

// ---------------- set-sum + phi head ----------------

__global__ __launch_bounds__(128) void phi_kernel(const float* __restrict__ pbuf,
                                                  const float* __restrict__ W1,
                                                  const float* __restrict__ b1,
                                                  const float* __restrict__ W2,
                                                  const float* __restrict__ b2,
                                                  float* __restrict__ out) {
    __shared__ float a[128];
    __shared__ float u[128];
    int s = blockIdx.x;
    int c = threadIdx.x;
    float acc = 0.f;
#pragma unroll
    for (int p = 0; p < PGS; ++p) acc += pbuf[(size_t)(s + p * SS) * 128 + c];
    a[c] = acc;
    __syncthreads();
    float acc1 = b1[c];
#pragma unroll 8
    for (int k = 0; k < 128; ++k) acc1 += a[k] * W1[k * 128 + c];
    u[c] = fmaxf(acc1, 0.f);
    __syncthreads();
    if (c < CC) {
        float acc2 = b2[c];
#pragma unroll 8
        for (int k = 0; k < 128; ++k) acc2 += u[k] * W2[k * CC + c];
        out[(size_t)s * CC + c] = acc2;
    }
}

// ---------------- launch ----------------

extern "C" void kernel_launch(void* const* d_in, const int* in_sizes, int n_in,
                              void* d_out, int out_size, void* d_ws, size_t ws_size,
                              hipStream_t stream) {
    const float* x   = (const float*)d_in[0];
    const int* ei    = (const int*)d_in[1];
    const float* W1  = (const float*)d_in[4];
    const float* b1  = (const float*)d_in[5];
    const float* W2  = (const float*)d_in[6];
    const float* b2  = (const float*)d_in[7];
    const float* W3  = (const float*)d_in[8];
    const float* b3  = (const float*)d_in[9];
    const float* pW1 = (const float*)d_in[10];
    const float* pb1 = (const float*)d_in[11];
    const float* pW2 = (const float*)d_in[12];
    const float* pb2 = (const float*)d_in[13];
    const float* fW1 = (const float*)d_in[14];
    const float* fb1 = (const float*)d_in[15];
    const float* fW2 = (const float*)d_in[16];
    const float* fb2 = (const float*)d_in[17];
    float* out = (float*)d_out;

    // workspace carve-up (256B aligned)
    char* p = (char*)d_ws;
    auto alloc = [&](size_t bytes) {
        char* r = p;
        p += (bytes + 255) & ~(size_t)255;
        return r;
    };
    int*      degi    = (int*)alloc((size_t)NN * 4);
    float*    dinv    = (float*)alloc((size_t)NN * 4);
    int*      row_ptr = (int*)alloc((size_t)(NN + 1) * 4);
    int*      cursor  = (int*)alloc((size_t)NN * 4);
    int*      bsum    = (int*)alloc(512 * 4);
    int*      col     = (int*)alloc((size_t)EE * 4);
    _Float16* bufA    = (_Float16*)alloc((size_t)NN * HH * 2);  // dinv-scaled XW (gather operand)
    __half*   bufB    = (__half*)alloc((size_t)NN * HH * 2);    // relu'd layer output
    float*    gemb    = (float*)alloc((size_t)GG * HH * 4);
    float*    pbuf    = (float*)alloc((size_t)GG * HH * 4);

    const int nblkN = (NN + 255) / 256;        // 391
    const int nblkE = (EE + 255) / 256;        // 6250

    // CSR build
    zero_int_kernel<<<nblkN, 256, 0, stream>>>(degi, NN);
    count_edges_kernel<<<nblkE, 256, 0, stream>>>(ei + EE, degi, EE);
    scan_chunk_kernel<<<nblkN, 256, 0, stream>>>(degi, row_ptr, bsum, NN);
    scan_bsums_kernel<<<1, 512, 0, stream>>>(bsum, nblkN);
    scan_finish_kernel<<<nblkN, 256, 0, stream>>>(row_ptr, bsum, NN);
    dinv_kernel<<<nblkN, 256, 0, stream>>>(degi, row_ptr, dinv, cursor, NN);
    fill_csr_kernel<<<nblkE * NCLS, 256, 0, stream>>>(ei, cursor, col, EE);

    const int gemmBlocks = (NN + 127) / 128;   // 782
    const int aggBlocks  = (NN + 3) / 4;       // 25000

    // layer 1
    gemm_mfma_kernel<true><<<gemmBlocks, 256, 0, stream>>>(x, W1, dinv, bufA, NN);
    aggregate_kernel<<<aggBlocks, 256, 0, stream>>>((const __half*)bufA, row_ptr, col, dinv, b1, bufB, NN);
    // layer 2
    gemm_mfma_kernel<false><<<gemmBlocks, 256, 0, stream>>>(bufB, W2, dinv, bufA, NN);
    aggregate_kernel<<<aggBlocks, 256, 0, stream>>>((const __half*)bufA, row_ptr, col, dinv, b2, bufB, NN);
    // layer 3
    gemm_mfma_kernel<false><<<gemmBlocks, 256, 0, stream>>>(bufB, W3, dinv, bufA, NN);
    aggregate_kernel<<<aggBlocks, 256, 0, stream>>>((const __half*)bufA, row_ptr, col, dinv, b3, bufB, NN);

    // pool -> [G,H]
    pool_kernel<<<(GG + 3) / 4, 256, 0, stream>>>(bufB, gemb);
    // DeepSets
    psi_kernel<<<GG, 128, 0, stream>>>(gemb, pW1, pb1, pW2, pb2, pbuf);
    phi_kernel<<<SS, 128, 0, stream>>>(pbuf, fW1, fb1, fW2, fb2, out);
}